// Round 2
// baseline (419.548 us; speedup 1.0000x reference)
//
#include <hip/hip_runtime.h>
#include <cmath>

#define BB 8
#define CC 256
#define CQ 64
#define NN 4096
constexpr float INV_N = 1.0f / 4096.0f;   // 2^-12: exact scale, foldable

typedef __attribute__((ext_vector_type(8))) short short8;
typedef __attribute__((ext_vector_type(4))) short short4v;
typedef __attribute__((ext_vector_type(4))) float float4v;

__device__ __forceinline__ short f2bf(float f) {
  union { float f; unsigned u; } x; x.f = f;
  unsigned r = x.u + 0x7fffu + ((x.u >> 16) & 1u);
  return (short)(r >> 16);
}

// ---------------------------------------------------------------------------
// One-time fp32 -> bf16 conversion of all conv weights into workspace.
// ---------------------------------------------------------------------------
__global__ void wconv_kernel(const float* __restrict__ wq,
                             const float* __restrict__ wk,
                             const float* __restrict__ wv,
                             const float* __restrict__ wg,
                             short* __restrict__ wqb, short* __restrict__ wkb,
                             short* __restrict__ wvb, short* __restrict__ wgb) {
  const int t = blockIdx.x * 256 + threadIdx.x;
  const float* src;
  short* dst;
  int idx;
  if (t < 4096)        { src = wq; dst = wqb; idx = t; }
  else if (t < 8192)   { src = wk; dst = wkb; idx = t - 4096; }
  else if (t < 24576)  { src = wv; dst = wvb; idx = t - 8192; }
  else                 { src = wg; dst = wgb; idx = t - 24576; }
  const float4 v = *reinterpret_cast<const float4*>(&src[(size_t)idx * 4]);
  short4v o;
  o[0] = f2bf(v.x); o[1] = f2bf(v.y); o[2] = f2bf(v.z); o[3] = f2bf(v.w);
  *reinterpret_cast<short4v*>(&dst[(size_t)idx * 4]) = o;
}

// ---------------------------------------------------------------------------
// Fused q/k/v conv1x1 via bf16 MFMA, v3: n-tile 32 (was 64) -> 1024 blocks,
// 4 blocks/CU (was 2). Same total work, 2x wave-level parallelism to cover
// the lockstep stage->barrier->MFMA critical path.
// grid (B, NN/32): flat id % 8 == b -> per-XCD L2 locality for attn.
// ---------------------------------------------------------------------------
__global__ __launch_bounds__(256, 4) void qkv_kernel(
    const float* __restrict__ X,
    const short* __restrict__ wqb, const float* __restrict__ bq,
    const short* __restrict__ wkb, const float* __restrict__ bk,
    const short* __restrict__ wvb, const float* __restrict__ bv,
    short* __restrict__ qt, short* __restrict__ kt, short* __restrict__ vbf) {
  __shared__ short xt[32 * 272];   // [n][c] bf16, 17408 B
  __shared__ short Os[64 * 40];    // v-output staging [o][n], 5120 B
  const int tid = threadIdx.x;
  const int wid = tid >> 6;
  const int lane = tid & 63, quad = lane >> 4, l16 = lane & 15;
  const int b = blockIdx.x, n0 = blockIdx.y * 32;

  // stage x tile -> xt[n][c] bf16 (transpose, fp32->bf16); 8 float4/thread
#pragma unroll 4
  for (int p = 0; p < 8; ++p) {
    const int idx = p * 256 + tid;
    const int c = idx >> 3;
    const int n4 = (idx & 7) * 4;
    const float4 x4 = *reinterpret_cast<const float4*>(
        &X[((size_t)b * CC + c) * NN + n0 + n4]);
    xt[(n4 + 0) * 272 + c] = f2bf(x4.x);
    xt[(n4 + 1) * 272 + c] = f2bf(x4.y);
    xt[(n4 + 2) * 272 + c] = f2bf(x4.z);
    xt[(n4 + 3) * 272 + c] = f2bf(x4.w);
  }
  __syncthreads();

  for (int ch = 0; ch < 6; ++ch) {
    const short* W; const float* bias; int obase;
    if (ch == 0)      { W = wqb; bias = bq; obase = 0; }
    else if (ch == 1) { W = wkb; bias = bk; obase = 0; }
    else { W = wvb + (size_t)(ch - 2) * 64 * CC; bias = bv + (ch - 2) * 64; obase = (ch - 2) * 64; }

    float4v acc[2];
#pragma unroll
    for (int tm = 0; tm < 2; ++tm) acc[tm] = float4v{0.f, 0.f, 0.f, 0.f};

    const short* wrow = &W[(size_t)(wid * 16 + l16) * CC + quad * 8];
    short8 a_cur = *reinterpret_cast<const short8*>(wrow);
#pragma unroll
    for (int kk = 0; kk < 8; ++kk) {
      short8 a_nxt = a_cur;
      if (kk < 7) a_nxt = *reinterpret_cast<const short8*>(wrow + (kk + 1) * 32);
#pragma unroll
      for (int tm = 0; tm < 2; ++tm) {
        const short8 bfrag = *reinterpret_cast<const short8*>(
            &xt[(tm * 16 + l16) * 272 + kk * 32 + quad * 8]);
        acc[tm] = __builtin_amdgcn_mfma_f32_16x16x32_bf16(a_cur, bfrag, acc[tm], 0, 0, 0);
      }
      a_cur = a_nxt;
    }

    // C layout: row o_local = wid*16 + quad*4 + r, col n_local = tm*16 + l16
    if (ch < 2) {
      short* dst = (ch == 0) ? qt : kt;
#pragma unroll
      for (int tm = 0; tm < 2; ++tm) {
        short4v pk;
#pragma unroll
        for (int r = 0; r < 4; ++r)
          pk[r] = f2bf(acc[tm][r] + bias[wid * 16 + quad * 4 + r]);
        *reinterpret_cast<short4v*>(
            &dst[((size_t)b * NN + n0 + tm * 16 + l16) * 64 + wid * 16 + quad * 4]) = pk;
      }
    } else {
      __syncthreads();  // previous chunk's Os reads complete
#pragma unroll
      for (int tm = 0; tm < 2; ++tm)
#pragma unroll
        for (int r = 0; r < 4; ++r)
          Os[(wid * 16 + quad * 4 + r) * 40 + tm * 16 + l16] =
              f2bf(acc[tm][r] + bias[wid * 16 + quad * 4 + r]);
      __syncthreads();
      const int o = tid >> 2, ng = (tid & 3) * 8;
      const short8 s0 = *reinterpret_cast<const short8*>(&Os[o * 40 + ng]);
      short* vp = &vbf[((size_t)b * CC + obase + o) * NN + n0 + ng];
      *reinterpret_cast<short8*>(vp) = s0;
    }
  }
}

// ---------------------------------------------------------------------------
// Fused MFMA attention + gamma conv, v4:
//  - m-tile 32 (was 64) -> grid (B, 128), 4 blocks/CU, 16 waves/CU.
//    Splitting along m duplicates no work (QK^T, elu, PV all split; gamma
//    epilogue keeps all 256 channels per block).
//  - INV_N (=2^-12, exact) folded out of per-iter elu into one epilogue
//    scale of acc — bit-identical numerics.
//  - loads issued at iter top; barrier drains vmcnt anyway, TLP (4 indep
//    blocks/CU) hides the latency instead of register prefetch.
// ---------------------------------------------------------------------------
__global__ __launch_bounds__(256, 4) void attn_kernel(
    const short* __restrict__ qt, const short* __restrict__ kt,
    const short* __restrict__ vbf, const short* __restrict__ wgb,
    const float* __restrict__ bg, float* __restrict__ out) {
  __shared__ short smem[8448];    // 16896 B
  short* Es0 = smem;              // [32 m][72 n]
  short* Es1 = smem + 2304;
  short* Outs = smem;             // [32 m][264 c] epilogue alias

  const int tid = threadIdx.x;
  const int wid = tid >> 6;
  const int lane = tid & 63, quad = lane >> 4, l16 = lane & 15;
  const int b = blockIdx.x, m0 = blockIdx.y * 32;

  // k fragments: resident in registers for the whole kernel (m-tile 32)
  short8 bkf[2][2];
#pragma unroll
  for (int tm = 0; tm < 2; ++tm)
#pragma unroll
    for (int kk = 0; kk < 2; ++kk)
      bkf[tm][kk] = *reinterpret_cast<const short8*>(
          &kt[((size_t)b * NN + m0 + tm * 16 + l16) * 64 + kk * 32 + quad * 8]);

  const short* qp = &qt[((size_t)b * NN + wid * 16 + l16) * 64 + quad * 8];
  const short* vp0 = &vbf[((size_t)b * CC + wid * 64 +  0 + l16) * NN + quad * 8];
  const short* vp1 = &vbf[((size_t)b * CC + wid * 64 + 16 + l16) * NN + quad * 8];
  const short* vp2 = &vbf[((size_t)b * CC + wid * 64 + 32 + l16) * NN + quad * 8];
  const short* vp3 = &vbf[((size_t)b * CC + wid * 64 + 48 + l16) * NN + quad * 8];

  float4v acc[4][2];
#pragma unroll
  for (int i = 0; i < 4; ++i)
#pragma unroll
    for (int j = 0; j < 2; ++j) acc[i][j] = float4v{0.f, 0.f, 0.f, 0.f};

  for (int it = 0; it < 64; ++it) {
    short* Esw = (it & 1) ? Es1 : Es0;

    // this iter's v and q fragments — all vmem issued up front
    short8 av[4][2];
    av[0][0] = *reinterpret_cast<const short8*>(vp0);
    av[0][1] = *reinterpret_cast<const short8*>(vp0 + 32);
    av[1][0] = *reinterpret_cast<const short8*>(vp1);
    av[1][1] = *reinterpret_cast<const short8*>(vp1 + 32);
    av[2][0] = *reinterpret_cast<const short8*>(vp2);
    av[2][1] = *reinterpret_cast<const short8*>(vp2 + 32);
    av[3][0] = *reinterpret_cast<const short8*>(vp3);
    av[3][1] = *reinterpret_cast<const short8*>(vp3 + 32);
    const short8 aq0 = *reinterpret_cast<const short8*>(qp);
    const short8 aq1 = *reinterpret_cast<const short8*>(qp + 32);

    // S = q^T k (K=64 via two MFMAs per m-tile)
    float4v s[2];
#pragma unroll
    for (int tm = 0; tm < 2; ++tm) {
      float4v t = {0.f, 0.f, 0.f, 0.f};
      t = __builtin_amdgcn_mfma_f32_16x16x32_bf16(aq0, bkf[tm][0], t, 0, 0, 0);
      t = __builtin_amdgcn_mfma_f32_16x16x32_bf16(aq1, bkf[tm][1], t, 0, 0, 0);
      s[tm] = t;
    }

    // elu (unscaled; INV_N folded into epilogue) -> Es
    // C layout: m = tm*16+l16, n = wid*16+quad*4+r
#pragma unroll
    for (int tm = 0; tm < 2; ++tm) {
      short4v pk;
#pragma unroll
      for (int r = 0; r < 4; ++r) {
        float sv = s[tm][r];
        sv = (sv > 0.f) ? sv : (__expf(sv) - 1.f);
        pk[r] = f2bf(sv);
      }
      *reinterpret_cast<short4v*>(
          &Esw[(tm * 16 + l16) * 72 + wid * 16 + quad * 4]) = pk;
    }
    __syncthreads();

    // PV: acc[c-tile][m-tile] += V E
#pragma unroll
    for (int tm = 0; tm < 2; ++tm) {
      const short8 be0 = *reinterpret_cast<const short8*>(
          &Esw[(tm * 16 + l16) * 72 + quad * 8]);
      const short8 be1 = *reinterpret_cast<const short8*>(
          &Esw[(tm * 16 + l16) * 72 + 32 + quad * 8]);
      acc[0][tm] = __builtin_amdgcn_mfma_f32_16x16x32_bf16(av[0][0], be0, acc[0][tm], 0, 0, 0);
      acc[0][tm] = __builtin_amdgcn_mfma_f32_16x16x32_bf16(av[0][1], be1, acc[0][tm], 0, 0, 0);
      acc[1][tm] = __builtin_amdgcn_mfma_f32_16x16x32_bf16(av[1][0], be0, acc[1][tm], 0, 0, 0);
      acc[1][tm] = __builtin_amdgcn_mfma_f32_16x16x32_bf16(av[1][1], be1, acc[1][tm], 0, 0, 0);
      acc[2][tm] = __builtin_amdgcn_mfma_f32_16x16x32_bf16(av[2][0], be0, acc[2][tm], 0, 0, 0);
      acc[2][tm] = __builtin_amdgcn_mfma_f32_16x16x32_bf16(av[2][1], be1, acc[2][tm], 0, 0, 0);
      acc[3][tm] = __builtin_amdgcn_mfma_f32_16x16x32_bf16(av[3][0], be0, acc[3][tm], 0, 0, 0);
      acc[3][tm] = __builtin_amdgcn_mfma_f32_16x16x32_bf16(av[3][1], be1, acc[3][tm], 0, 0, 0);
    }

    qp += 64 * 64;
    vp0 += 64; vp1 += 64; vp2 += 64; vp3 += 64;
  }

  // ---- epilogue: gamma conv via MFMA ----
  __syncthreads();
#pragma unroll
  for (int tc = 0; tc < 4; ++tc)
#pragma unroll
    for (int tm = 0; tm < 2; ++tm) {
      short4v pk;
#pragma unroll
      for (int r = 0; r < 4; ++r) pk[r] = f2bf(acc[tc][tm][r] * INV_N);
      *reinterpret_cast<short4v*>(
          &Outs[(tm * 16 + l16) * 264 + wid * 64 + tc * 16 + quad * 4]) = pk;
    }
  __syncthreads();

#pragma unroll
  for (int i = 0; i < 4; ++i)
#pragma unroll
    for (int j = 0; j < 2; ++j) acc[i][j] = float4v{0.f, 0.f, 0.f, 0.f};

  for (int ks8 = 0; ks8 < 8; ++ks8) {
    short8 ag[4];
#pragma unroll
    for (int to = 0; to < 4; ++to)
      ag[to] = *reinterpret_cast<const short8*>(
          &wgb[(size_t)(wid * 64 + to * 16 + l16) * CC + ks8 * 32 + quad * 8]);
    short8 bo[2];
#pragma unroll
    for (int tm = 0; tm < 2; ++tm)
      bo[tm] = *reinterpret_cast<const short8*>(
          &Outs[(tm * 16 + l16) * 264 + ks8 * 32 + quad * 8]);
#pragma unroll
    for (int to = 0; to < 4; ++to)
#pragma unroll
      for (int tm = 0; tm < 2; ++tm)
        acc[to][tm] =
            __builtin_amdgcn_mfma_f32_16x16x32_bf16(ag[to], bo[tm], acc[to][tm], 0, 0, 0);
  }

#pragma unroll
  for (int to = 0; to < 4; ++to) {
#pragma unroll
    for (int r = 0; r < 4; ++r) {
      const int o = wid * 64 + to * 16 + quad * 4 + r;
      const float bgv = bg[o];
#pragma unroll
      for (int tm = 0; tm < 2; ++tm) {
        out[((size_t)b * CC + o) * NN + m0 + tm * 16 + l16] =
            acc[to][tm][r] + bgv;
      }
    }
  }
}

// ---------------------------------------------------------------------------
extern "C" void kernel_launch(void* const* d_in, const int* in_sizes, int n_in,
                              void* d_out, int out_size, void* d_ws,
                              size_t ws_size, hipStream_t stream) {
  const float* x  = (const float*)d_in[0];
  const float* wq = (const float*)d_in[1];
  const float* bq = (const float*)d_in[2];
  const float* wk = (const float*)d_in[3];
  const float* bk = (const float*)d_in[4];
  const float* wv = (const float*)d_in[5];
  const float* bv = (const float*)d_in[6];
  const float* wg = (const float*)d_in[7];
  const float* bg = (const float*)d_in[8];
  float* out = (float*)d_out;

  short* qt  = (short*)d_ws;                     // [B][N][64] bf16, 4 MB
  short* kt  = qt + (size_t)BB * NN * CQ;        // 4 MB
  short* vbf = kt + (size_t)BB * NN * CQ;        // [B][C][N] bf16, 16 MB
  short* wqb = vbf + (size_t)BB * CC * NN;       // bf16 weights, 320 KB total
  short* wkb = wqb + (size_t)CQ * CC;
  short* wvb = wkb + (size_t)CQ * CC;
  short* wgb = wvb + (size_t)CC * CC;

  wconv_kernel<<<dim3(160), 256, 0, stream>>>(wq, wk, wv, wg, wqb, wkb, wvb, wgb);
  qkv_kernel<<<dim3(BB, NN / 32), 256, 0, stream>>>(x, wqb, bq, wkb, bk, wvb, bv,
                                                    qt, kt, vbf);
  attn_kernel<<<dim3(BB, NN / 32), 256, 0, stream>>>(qt, kt, vbf, wgb, bg, out);
}

// Round 3
// 276.945 us; speedup vs baseline: 1.5149x; 1.5149x over previous
//
#include <hip/hip_runtime.h>
#include <cmath>

#define BB 8
#define CC 256
#define CQ 64
#define NN 4096
constexpr float INV_N = 1.0f / 4096.0f;   // 2^-12: exact scale, folded into epilogue

typedef __attribute__((ext_vector_type(8))) short short8;
typedef __attribute__((ext_vector_type(4))) short short4v;
typedef __attribute__((ext_vector_type(4))) float float4v;

__device__ __forceinline__ short f2bf(float f) {
  union { float f; unsigned u; } x; x.f = f;
  unsigned r = x.u + 0x7fffu + ((x.u >> 16) & 1u);
  return (short)(r >> 16);
}

// ---------------------------------------------------------------------------
// One-time fp32 -> bf16 conversion of all conv weights into workspace.
// ---------------------------------------------------------------------------
__global__ void wconv_kernel(const float* __restrict__ wq,
                             const float* __restrict__ wk,
                             const float* __restrict__ wv,
                             const float* __restrict__ wg,
                             short* __restrict__ wqb, short* __restrict__ wkb,
                             short* __restrict__ wvb, short* __restrict__ wgb) {
  const int t = blockIdx.x * 256 + threadIdx.x;
  const float* src;
  short* dst;
  int idx;
  if (t < 4096)        { src = wq; dst = wqb; idx = t; }
  else if (t < 8192)   { src = wk; dst = wkb; idx = t - 4096; }
  else if (t < 24576)  { src = wv; dst = wvb; idx = t - 8192; }
  else                 { src = wg; dst = wgb; idx = t - 24576; }
  const float4 v = *reinterpret_cast<const float4*>(&src[(size_t)idx * 4]);
  short4v o;
  o[0] = f2bf(v.x); o[1] = f2bf(v.y); o[2] = f2bf(v.z); o[3] = f2bf(v.w);
  *reinterpret_cast<short4v*>(&dst[(size_t)idx * 4]) = o;
}

// ---------------------------------------------------------------------------
// Fused q/k/v conv1x1 via bf16 MFMA, v4 (round-1 shape + latency-chain fixes):
//  - n-tile 64, grid (B, 64), 2 blocks/CU  (the measured-best shape)
//  - x staging: all 16 float4 loads issued BEFORE any convert/LDS write
//    (one HBM latency exposure instead of 4)
//  - weight frags: all 8 per chunk preloaded up front (one L2 latency per
//    chunk instead of 8 serialized ~300cy loads behind a 1-deep prefetch)
// ---------------------------------------------------------------------------
__global__ __launch_bounds__(256, 2) void qkv_kernel(
    const float* __restrict__ X,
    const short* __restrict__ wqb, const float* __restrict__ bq,
    const short* __restrict__ wkb, const float* __restrict__ bk,
    const short* __restrict__ wvb, const float* __restrict__ bv,
    short* __restrict__ qt, short* __restrict__ kt, short* __restrict__ vbf) {
  __shared__ short xt[64 * 272];   // [n][c] bf16, stride 272 (16B-aligned rows)
  __shared__ short Os[64 * 72];    // v-output staging [o][n]
  const int tid = threadIdx.x;
  const int wid = tid >> 6;
  const int lane = tid & 63, quad = lane >> 4, l16 = lane & 15;
  const int b = blockIdx.x, n0 = blockIdx.y * 64;

  // stage x tile -> xt[n][c] bf16: issue ALL loads, then convert+write
  float4 xb[16];
#pragma unroll
  for (int p = 0; p < 16; ++p) {
    const int idx = p * 256 + tid;
    const int c = idx >> 4;
    const int n4 = (idx & 15) * 4;
    xb[p] = *reinterpret_cast<const float4*>(
        &X[((size_t)b * CC + c) * NN + n0 + n4]);
  }
#pragma unroll
  for (int p = 0; p < 16; ++p) {
    const int idx = p * 256 + tid;
    const int c = idx >> 4;
    const int n4 = (idx & 15) * 4;
    xt[(n4 + 0) * 272 + c] = f2bf(xb[p].x);
    xt[(n4 + 1) * 272 + c] = f2bf(xb[p].y);
    xt[(n4 + 2) * 272 + c] = f2bf(xb[p].z);
    xt[(n4 + 3) * 272 + c] = f2bf(xb[p].w);
  }
  __syncthreads();

  for (int ch = 0; ch < 6; ++ch) {
    const short* W; const float* bias; int obase;
    if (ch == 0)      { W = wqb; bias = bq; obase = 0; }
    else if (ch == 1) { W = wkb; bias = bk; obase = 0; }
    else { W = wvb + (size_t)(ch - 2) * 64 * CC; bias = bv + (ch - 2) * 64; obase = (ch - 2) * 64; }

    float4v acc[4];
#pragma unroll
    for (int tm = 0; tm < 4; ++tm) acc[tm] = float4v{0.f, 0.f, 0.f, 0.f};

    // preload ALL weight frags for this chunk (32 VGPR), then run MFMAs
    const short* wrow = &W[(size_t)(wid * 16 + l16) * CC + quad * 8];
    short8 wf[8];
#pragma unroll
    for (int kk = 0; kk < 8; ++kk)
      wf[kk] = *reinterpret_cast<const short8*>(wrow + kk * 32);

#pragma unroll
    for (int kk = 0; kk < 8; ++kk) {
#pragma unroll
      for (int tm = 0; tm < 4; ++tm) {
        const short8 bfrag = *reinterpret_cast<const short8*>(
            &xt[(tm * 16 + l16) * 272 + kk * 32 + quad * 8]);
        acc[tm] = __builtin_amdgcn_mfma_f32_16x16x32_bf16(wf[kk], bfrag, acc[tm], 0, 0, 0);
      }
    }

    // C layout: row o_local = wid*16 + quad*4 + r, col n_local = tm*16 + l16
    if (ch < 2) {
      short* dst = (ch == 0) ? qt : kt;
#pragma unroll
      for (int tm = 0; tm < 4; ++tm) {
        short4v pk;
#pragma unroll
        for (int r = 0; r < 4; ++r)
          pk[r] = f2bf(acc[tm][r] + bias[wid * 16 + quad * 4 + r]);
        *reinterpret_cast<short4v*>(
            &dst[((size_t)b * NN + n0 + tm * 16 + l16) * 64 + wid * 16 + quad * 4]) = pk;
      }
    } else {
      __syncthreads();  // previous chunk's Os reads complete
#pragma unroll
      for (int tm = 0; tm < 4; ++tm)
#pragma unroll
        for (int r = 0; r < 4; ++r)
          Os[(wid * 16 + quad * 4 + r) * 72 + tm * 16 + l16] =
              f2bf(acc[tm][r] + bias[wid * 16 + quad * 4 + r]);
      __syncthreads();
      const int o = tid >> 2, ng = (tid & 3) * 16;
      const short8 s0 = *reinterpret_cast<const short8*>(&Os[o * 72 + ng]);
      const short8 s1 = *reinterpret_cast<const short8*>(&Os[o * 72 + ng + 8]);
      short* vp = &vbf[((size_t)b * CC + obase + o) * NN + n0 + ng];
      *reinterpret_cast<short8*>(vp) = s0;
      *reinterpret_cast<short8*>(vp + 8) = s1;
    }
  }
}

// ---------------------------------------------------------------------------
// Fused MFMA attention + gamma conv, v5 (round-1 shape + barrier amortization):
//  - m-tile 64, grid (B, 64), 2 blocks/CU  (the measured-best shape)
//  - PAIR iterations: 2 n-blocks per barrier via quad-buffered Es
//    -> 32 barriers/vmcnt-drains instead of 64; 80 MFMA/wave per barrier
//  - avB (second half's V frags) issued right AFTER the barrier: PV-A's
//    32 MFMA (~600cy) cover their L2 latency
//  - INV_N (2^-12, exact) folded into epilogue scale — bit-identical
// WAR safety: pair p uses buffers (p&1); writes to a buffer pair happen only
// after the barrier of pair p+1, by which time pair p's reads are done.
// ---------------------------------------------------------------------------
__global__ __launch_bounds__(256, 2) void attn_kernel(
    const short* __restrict__ qt, const short* __restrict__ kt,
    const short* __restrict__ vbf, const short* __restrict__ wgb,
    const float* __restrict__ bg, float* __restrict__ out) {
  __shared__ short smem[18432];   // 36864 B: 4 Es buffers of [64 m][72 n]
  short* Outs = smem;             // [64 m][264 c] epilogue alias (16896 shorts)

  const int tid = threadIdx.x;
  const int wid = tid >> 6;
  const int lane = tid & 63, quad = lane >> 4, l16 = lane & 15;
  const int b = blockIdx.x, m0 = blockIdx.y * 64;

  // k fragments: resident in registers for the whole kernel
  short8 bkf[4][2];
#pragma unroll
  for (int tm = 0; tm < 4; ++tm)
#pragma unroll
    for (int kk = 0; kk < 2; ++kk)
      bkf[tm][kk] = *reinterpret_cast<const short8*>(
          &kt[((size_t)b * NN + m0 + tm * 16 + l16) * 64 + kk * 32 + quad * 8]);

  const short* qp = &qt[((size_t)b * NN + wid * 16 + l16) * 64 + quad * 8];
  const short* vp0 = &vbf[((size_t)b * CC + wid * 64 +  0 + l16) * NN + quad * 8];
  const short* vp1 = &vbf[((size_t)b * CC + wid * 64 + 16 + l16) * NN + quad * 8];
  const short* vp2 = &vbf[((size_t)b * CC + wid * 64 + 32 + l16) * NN + quad * 8];
  const short* vp3 = &vbf[((size_t)b * CC + wid * 64 + 48 + l16) * NN + quad * 8];

  float4v acc[4][4];
#pragma unroll
  for (int i = 0; i < 4; ++i)
#pragma unroll
    for (int j = 0; j < 4; ++j) acc[i][j] = float4v{0.f, 0.f, 0.f, 0.f};

  for (int p = 0; p < 32; ++p) {
    short* EA = smem + ((p & 1) ? 9216 : 0);
    short* EB = smem + ((p & 1) ? 13824 : 4608);

    // q frags for both halves + V frags for half A — issued up front
    const short8 aqA0 = *reinterpret_cast<const short8*>(qp);
    const short8 aqA1 = *reinterpret_cast<const short8*>(qp + 32);
    const short8 aqB0 = *reinterpret_cast<const short8*>(qp + 4096);
    const short8 aqB1 = *reinterpret_cast<const short8*>(qp + 4096 + 32);
    short8 avA[4][2];
    avA[0][0] = *reinterpret_cast<const short8*>(vp0);
    avA[0][1] = *reinterpret_cast<const short8*>(vp0 + 32);
    avA[1][0] = *reinterpret_cast<const short8*>(vp1);
    avA[1][1] = *reinterpret_cast<const short8*>(vp1 + 32);
    avA[2][0] = *reinterpret_cast<const short8*>(vp2);
    avA[2][1] = *reinterpret_cast<const short8*>(vp2 + 32);
    avA[3][0] = *reinterpret_cast<const short8*>(vp3);
    avA[3][1] = *reinterpret_cast<const short8*>(vp3 + 32);

    // S and elu for half A -> EA
#pragma unroll
    for (int tm = 0; tm < 4; ++tm) {
      float4v t = {0.f, 0.f, 0.f, 0.f};
      t = __builtin_amdgcn_mfma_f32_16x16x32_bf16(aqA0, bkf[tm][0], t, 0, 0, 0);
      t = __builtin_amdgcn_mfma_f32_16x16x32_bf16(aqA1, bkf[tm][1], t, 0, 0, 0);
      short4v pk;
#pragma unroll
      for (int r = 0; r < 4; ++r) {
        float sv = t[r];
        sv = (sv > 0.f) ? sv : (__expf(sv) - 1.f);
        pk[r] = f2bf(sv);
      }
      *reinterpret_cast<short4v*>(
          &EA[(tm * 16 + l16) * 72 + wid * 16 + quad * 4]) = pk;
    }

    // S and elu for half B -> EB
#pragma unroll
    for (int tm = 0; tm < 4; ++tm) {
      float4v t = {0.f, 0.f, 0.f, 0.f};
      t = __builtin_amdgcn_mfma_f32_16x16x32_bf16(aqB0, bkf[tm][0], t, 0, 0, 0);
      t = __builtin_amdgcn_mfma_f32_16x16x32_bf16(aqB1, bkf[tm][1], t, 0, 0, 0);
      short4v pk;
#pragma unroll
      for (int r = 0; r < 4; ++r) {
        float sv = t[r];
        sv = (sv > 0.f) ? sv : (__expf(sv) - 1.f);
        pk[r] = f2bf(sv);
      }
      *reinterpret_cast<short4v*>(
          &EB[(tm * 16 + l16) * 72 + wid * 16 + quad * 4]) = pk;
    }
    __syncthreads();

    // half B's V frags — issued now; PV-A's MFMAs cover their latency
    short8 avB[4][2];
    avB[0][0] = *reinterpret_cast<const short8*>(vp0 + 64);
    avB[0][1] = *reinterpret_cast<const short8*>(vp0 + 96);
    avB[1][0] = *reinterpret_cast<const short8*>(vp1 + 64);
    avB[1][1] = *reinterpret_cast<const short8*>(vp1 + 96);
    avB[2][0] = *reinterpret_cast<const short8*>(vp2 + 64);
    avB[2][1] = *reinterpret_cast<const short8*>(vp2 + 96);
    avB[3][0] = *reinterpret_cast<const short8*>(vp3 + 64);
    avB[3][1] = *reinterpret_cast<const short8*>(vp3 + 96);

    // PV half A
#pragma unroll
    for (int tm = 0; tm < 4; ++tm) {
      const short8 be0 = *reinterpret_cast<const short8*>(
          &EA[(tm * 16 + l16) * 72 + quad * 8]);
      const short8 be1 = *reinterpret_cast<const short8*>(
          &EA[(tm * 16 + l16) * 72 + 32 + quad * 8]);
#pragma unroll
      for (int tc = 0; tc < 4; ++tc) {
        acc[tc][tm] = __builtin_amdgcn_mfma_f32_16x16x32_bf16(avA[tc][0], be0, acc[tc][tm], 0, 0, 0);
        acc[tc][tm] = __builtin_amdgcn_mfma_f32_16x16x32_bf16(avA[tc][1], be1, acc[tc][tm], 0, 0, 0);
      }
    }
    // PV half B
#pragma unroll
    for (int tm = 0; tm < 4; ++tm) {
      const short8 be0 = *reinterpret_cast<const short8*>(
          &EB[(tm * 16 + l16) * 72 + quad * 8]);
      const short8 be1 = *reinterpret_cast<const short8*>(
          &EB[(tm * 16 + l16) * 72 + 32 + quad * 8]);
#pragma unroll
      for (int tc = 0; tc < 4; ++tc) {
        acc[tc][tm] = __builtin_amdgcn_mfma_f32_16x16x32_bf16(avB[tc][0], be0, acc[tc][tm], 0, 0, 0);
        acc[tc][tm] = __builtin_amdgcn_mfma_f32_16x16x32_bf16(avB[tc][1], be1, acc[tc][tm], 0, 0, 0);
      }
    }

    qp += 2 * 64 * 64;
    vp0 += 128; vp1 += 128; vp2 += 128; vp3 += 128;
  }

  // ---- epilogue: gamma conv via MFMA (INV_N applied here, exact) ----
  __syncthreads();
#pragma unroll
  for (int tc = 0; tc < 4; ++tc)
#pragma unroll
    for (int tm = 0; tm < 4; ++tm) {
      short4v pk;
#pragma unroll
      for (int r = 0; r < 4; ++r) pk[r] = f2bf(acc[tc][tm][r] * INV_N);
      *reinterpret_cast<short4v*>(
          &Outs[(tm * 16 + l16) * 264 + wid * 64 + tc * 16 + quad * 4]) = pk;
    }
  __syncthreads();

#pragma unroll
  for (int i = 0; i < 4; ++i)
#pragma unroll
    for (int j = 0; j < 4; ++j) acc[i][j] = float4v{0.f, 0.f, 0.f, 0.f};

  for (int ks8 = 0; ks8 < 8; ++ks8) {
    short8 ag[4];
#pragma unroll
    for (int to = 0; to < 4; ++to)
      ag[to] = *reinterpret_cast<const short8*>(
          &wgb[(size_t)(wid * 64 + to * 16 + l16) * CC + ks8 * 32 + quad * 8]);
    short8 bo[4];
#pragma unroll
    for (int tm = 0; tm < 4; ++tm)
      bo[tm] = *reinterpret_cast<const short8*>(
          &Outs[(tm * 16 + l16) * 264 + ks8 * 32 + quad * 8]);
#pragma unroll
    for (int to = 0; to < 4; ++to)
#pragma unroll
      for (int tm = 0; tm < 4; ++tm)
        acc[to][tm] =
            __builtin_amdgcn_mfma_f32_16x16x32_bf16(ag[to], bo[tm], acc[to][tm], 0, 0, 0);
  }

#pragma unroll
  for (int to = 0; to < 4; ++to) {
#pragma unroll
    for (int r = 0; r < 4; ++r) {
      const int o = wid * 64 + to * 16 + quad * 4 + r;
      const float bgv = bg[o];
#pragma unroll
      for (int tm = 0; tm < 4; ++tm) {
        out[((size_t)b * CC + o) * NN + m0 + tm * 16 + l16] =
            acc[to][tm][r] + bgv;
      }
    }
  }
}

// ---------------------------------------------------------------------------
extern "C" void kernel_launch(void* const* d_in, const int* in_sizes, int n_in,
                              void* d_out, int out_size, void* d_ws,
                              size_t ws_size, hipStream_t stream) {
  const float* x  = (const float*)d_in[0];
  const float* wq = (const float*)d_in[1];
  const float* bq = (const float*)d_in[2];
  const float* wk = (const float*)d_in[3];
  const float* bk = (const float*)d_in[4];
  const float* wv = (const float*)d_in[5];
  const float* bv = (const float*)d_in[6];
  const float* wg = (const float*)d_in[7];
  const float* bg = (const float*)d_in[8];
  float* out = (float*)d_out;

  short* qt  = (short*)d_ws;                     // [B][N][64] bf16, 4 MB
  short* kt  = qt + (size_t)BB * NN * CQ;        // 4 MB
  short* vbf = kt + (size_t)BB * NN * CQ;        // [B][C][N] bf16, 16 MB
  short* wqb = vbf + (size_t)BB * CC * NN;       // bf16 weights, 320 KB total
  short* wkb = wqb + (size_t)CQ * CC;
  short* wvb = wkb + (size_t)CQ * CC;
  short* wgb = wvb + (size_t)CC * CC;

  wconv_kernel<<<dim3(160), 256, 0, stream>>>(wq, wk, wv, wg, wqb, wkb, wvb, wgb);
  qkv_kernel<<<dim3(BB, NN / 64), 256, 0, stream>>>(x, wqb, bq, wkb, bk, wvb, bv,
                                                    qt, kt, vbf);
  attn_kernel<<<dim3(BB, NN / 64), 256, 0, stream>>>(qt, kt, vbf, wgb, bg, out);
}

// Round 4
// 272.326 us; speedup vs baseline: 1.5406x; 1.0170x over previous
//
#include <hip/hip_runtime.h>
#include <cmath>

#define BB 8
#define CC 256
#define CQ 64
#define NN 4096
constexpr float INV_N = 1.0f / 4096.0f;   // 2^-12: exact, folded into epilogue

typedef __attribute__((ext_vector_type(8))) short short8;
typedef __attribute__((ext_vector_type(4))) short short4v;
typedef __attribute__((ext_vector_type(4))) float float4v;

__device__ __forceinline__ short f2bf(float f) {
  union { float f; unsigned u; } x; x.f = f;
  unsigned r = x.u + 0x7fffu + ((x.u >> 16) & 1u);
  return (short)(r >> 16);
}

// ---------------------------------------------------------------------------
// One-time fp32 -> bf16 conversion of all conv weights into workspace.
// ---------------------------------------------------------------------------
__global__ void wconv_kernel(const float* __restrict__ wq,
                             const float* __restrict__ wk,
                             const float* __restrict__ wv,
                             const float* __restrict__ wg,
                             short* __restrict__ wqb, short* __restrict__ wkb,
                             short* __restrict__ wvb, short* __restrict__ wgb) {
  const int t = blockIdx.x * 256 + threadIdx.x;
  const float* src;
  short* dst;
  int idx;
  if (t < 4096)        { src = wq; dst = wqb; idx = t; }
  else if (t < 8192)   { src = wk; dst = wkb; idx = t - 4096; }
  else if (t < 24576)  { src = wv; dst = wvb; idx = t - 8192; }
  else                 { src = wg; dst = wgb; idx = t - 24576; }
  const float4 v = *reinterpret_cast<const float4*>(&src[(size_t)idx * 4]);
  short4v o;
  o[0] = f2bf(v.x); o[1] = f2bf(v.y); o[2] = f2bf(v.z); o[3] = f2bf(v.w);
  *reinterpret_cast<short4v*>(&dst[(size_t)idx * 4]) = o;
}

// ---------------------------------------------------------------------------
// Fused q/k/v conv1x1, v5:
//  - x B-fragments hoisted to REGISTERS once (identical across all 6 output
//    chunks) -> 6x fewer LDS reads, LDS off the MFMA inner path
//  - xt stride 264 (was 272): frag reads 2-way (free), staging writes 8-way
//    (was 16-way)
//  - Os double-buffered -> 1 barrier per v-chunk (was 2)
// grid (B, 64), 256 threads, 2 blocks/CU.
// ---------------------------------------------------------------------------
__global__ __launch_bounds__(256, 2) void qkv_kernel(
    const float* __restrict__ X,
    const short* __restrict__ wqb, const float* __restrict__ bq,
    const short* __restrict__ wkb, const float* __restrict__ bk,
    const short* __restrict__ wvb, const float* __restrict__ bv,
    short* __restrict__ qt, short* __restrict__ kt, short* __restrict__ vbf) {
  __shared__ short xt[64 * 264];   // 33792 B; Os buffers alias after frag load
  const int tid = threadIdx.x;
  const int wid = tid >> 6;
  const int lane = tid & 63, quad = lane >> 4, l16 = lane & 15;
  const int b = blockIdx.x, n0 = blockIdx.y * 64;

  // stage x tile -> xt[n][c] bf16 (all loads issued before converts)
  float4 xb[16];
#pragma unroll
  for (int p = 0; p < 16; ++p) {
    const int idx = p * 256 + tid;
    const int c = idx >> 4;
    const int n4 = (idx & 15) * 4;
    xb[p] = *reinterpret_cast<const float4*>(
        &X[((size_t)b * CC + c) * NN + n0 + n4]);
  }
#pragma unroll
  for (int p = 0; p < 16; ++p) {
    const int idx = p * 256 + tid;
    const int c = idx >> 4;
    const int n4 = (idx & 15) * 4;
    xt[(n4 + 0) * 264 + c] = f2bf(xb[p].x);
    xt[(n4 + 1) * 264 + c] = f2bf(xb[p].y);
    xt[(n4 + 2) * 264 + c] = f2bf(xb[p].z);
    xt[(n4 + 3) * 264 + c] = f2bf(xb[p].w);
  }
  __syncthreads();

  // x B-fragments -> registers (same for every wave; covers full 64n x 256c)
  short8 bfr[8][4];
#pragma unroll
  for (int kk = 0; kk < 8; ++kk)
#pragma unroll
    for (int tm = 0; tm < 4; ++tm)
      bfr[kk][tm] = *reinterpret_cast<const short8*>(
          &xt[(tm * 16 + l16) * 264 + kk * 32 + quad * 8]);
  __syncthreads();   // xt dead; Os aliasing now safe

  short* Os0 = xt;          // [64 o][72 n]
  short* Os1 = xt + 4608;

  for (int ch = 0; ch < 6; ++ch) {
    const short* W; const float* bias; int obase;
    if (ch == 0)      { W = wqb; bias = bq; obase = 0; }
    else if (ch == 1) { W = wkb; bias = bk; obase = 0; }
    else { W = wvb + (size_t)(ch - 2) * 64 * CC; bias = bv + (ch - 2) * 64; obase = (ch - 2) * 64; }

    // weight frags for this chunk (batched: one L2 latency exposure)
    const short* wrow = &W[(size_t)(wid * 16 + l16) * CC + quad * 8];
    short8 wf[8];
#pragma unroll
    for (int kk = 0; kk < 8; ++kk)
      wf[kk] = *reinterpret_cast<const short8*>(wrow + kk * 32);

    float4v acc[4];
#pragma unroll
    for (int tm = 0; tm < 4; ++tm) acc[tm] = float4v{0.f, 0.f, 0.f, 0.f};
#pragma unroll
    for (int kk = 0; kk < 8; ++kk)
#pragma unroll
      for (int tm = 0; tm < 4; ++tm)
        acc[tm] = __builtin_amdgcn_mfma_f32_16x16x32_bf16(wf[kk], bfr[kk][tm], acc[tm], 0, 0, 0);

    // C layout: row o_local = wid*16 + quad*4 + r, col n_local = tm*16 + l16
    if (ch < 2) {
      short* dst = (ch == 0) ? qt : kt;
#pragma unroll
      for (int tm = 0; tm < 4; ++tm) {
        short4v pk;
#pragma unroll
        for (int r = 0; r < 4; ++r)
          pk[r] = f2bf(acc[tm][r] + bias[wid * 16 + quad * 4 + r]);
        *reinterpret_cast<short4v*>(
            &dst[((size_t)b * NN + n0 + tm * 16 + l16) * 64 + wid * 16 + quad * 4]) = pk;
      }
    } else {
      short* Os = (ch & 1) ? Os1 : Os0;   // double-buffered, 1 barrier/chunk
#pragma unroll
      for (int tm = 0; tm < 4; ++tm)
#pragma unroll
        for (int r = 0; r < 4; ++r)
          Os[(wid * 16 + quad * 4 + r) * 72 + tm * 16 + l16] =
              f2bf(acc[tm][r] + bias[wid * 16 + quad * 4 + r]);
      __syncthreads();
      const int o = tid >> 2, ng = (tid & 3) * 16;
      const short8 s0 = *reinterpret_cast<const short8*>(&Os[o * 72 + ng]);
      const short8 s1 = *reinterpret_cast<const short8*>(&Os[o * 72 + ng + 8]);
      short* vp = &vbf[((size_t)b * CC + obase + o) * NN + n0 + ng];
      *reinterpret_cast<short8*>(vp) = s0;
      *reinterpret_cast<short8*>(vp + 8) = s1;
    }
  }
}

// ---------------------------------------------------------------------------
// Fused MFMA attention + gamma conv, v6 — cross-iteration software pipeline:
// segment S_it (between barriers) does, in order:
//   issue v(it+1), q(it+2) loads
//   QK^T(it+1)   [8 MFMA, independent of PV(it)]
//   PV(it)       [32 MFMA — QK results mature underneath]
//   elu(it+1) -> write Es[(it+1)&1]
//   barrier
// -> 40 contiguous MFMAs per wave per segment; elu and all loads off the
// critical path. Es(j) lives in buffer j&1; the lgkmcnt-drain at each
// barrier protects the 2-deep buffer reuse.
// grid (B, 64), 256 threads, 2 blocks/CU.
// ---------------------------------------------------------------------------
__global__ __launch_bounds__(256, 2) void attn_kernel(
    const short* __restrict__ qt, const short* __restrict__ kt,
    const short* __restrict__ vbf, const short* __restrict__ wgb,
    const float* __restrict__ bg, float* __restrict__ out) {
  __shared__ short smem[16896];   // 33792 B
  short* Es0 = smem;              // [64 m][72 n]
  short* Es1 = smem + 4608;
  short* Outs = smem;             // [64 m][264 c] epilogue alias

  const int tid = threadIdx.x;
  const int wid = tid >> 6;
  const int lane = tid & 63, quad = lane >> 4, l16 = lane & 15;
  const int b = blockIdx.x, m0 = blockIdx.y * 64;

  // k fragments: resident in registers for the whole kernel
  short8 bkf[4][2];
#pragma unroll
  for (int tm = 0; tm < 4; ++tm)
#pragma unroll
    for (int kk = 0; kk < 2; ++kk)
      bkf[tm][kk] = *reinterpret_cast<const short8*>(
          &kt[((size_t)b * NN + m0 + tm * 16 + l16) * 64 + kk * 32 + quad * 8]);

  const short* qp = &qt[((size_t)b * NN + wid * 16 + l16) * 64 + quad * 8];
  const short* vrow[4];
#pragma unroll
  for (int tc = 0; tc < 4; ++tc)
    vrow[tc] = &vbf[((size_t)b * CC + wid * 64 + tc * 16 + l16) * NN + quad * 8];

  float4v acc[4][4];
#pragma unroll
  for (int i = 0; i < 4; ++i)
#pragma unroll
    for (int j = 0; j < 4; ++j) acc[i][j] = float4v{0.f, 0.f, 0.f, 0.f};

  // ---- prologue: v(0), q(0); QK(0)+elu -> Es0; preload q(1) ----
  short8 avA[4][2], avB[4][2];
#pragma unroll
  for (int tc = 0; tc < 4; ++tc) {
    avA[tc][0] = *reinterpret_cast<const short8*>(vrow[tc]);
    avA[tc][1] = *reinterpret_cast<const short8*>(vrow[tc] + 32);
  }
  short8 aqA0 = *reinterpret_cast<const short8*>(qp + (size_t)1 * 4096);
  short8 aqA1 = *reinterpret_cast<const short8*>(qp + (size_t)1 * 4096 + 32);
  short8 aqB0, aqB1;
  {
    const short8 aq0 = *reinterpret_cast<const short8*>(qp);
    const short8 aq1 = *reinterpret_cast<const short8*>(qp + 32);
#pragma unroll
    for (int tm = 0; tm < 4; ++tm) {
      float4v t = {0.f, 0.f, 0.f, 0.f};
      t = __builtin_amdgcn_mfma_f32_16x16x32_bf16(aq0, bkf[tm][0], t, 0, 0, 0);
      t = __builtin_amdgcn_mfma_f32_16x16x32_bf16(aq1, bkf[tm][1], t, 0, 0, 0);
      short4v pk;
#pragma unroll
      for (int r = 0; r < 4; ++r) {
        float sv = t[r];
        sv = (sv > 0.f) ? sv : (__expf(sv) - 1.f);
        pk[r] = f2bf(sv);
      }
      *reinterpret_cast<short4v*>(
          &Es0[(tm * 16 + l16) * 72 + wid * 16 + quad * 4]) = pk;
    }
  }
  __syncthreads();

  // avc = v(it) [consumed by PV(it)]; avn <- v(it+1)
  // aqc = q(it+1) [consumed by QK(it+1)]; aqn <- q(it+2)
  auto seg = [&](int it, short8 (&avc)[4][2], short8 (&avn)[4][2],
                 short8& aqc0, short8& aqc1, short8& aqn0, short8& aqn1) {
    const int nb1 = (it + 1) * 64;
#pragma unroll
    for (int tc = 0; tc < 4; ++tc) {
      avn[tc][0] = *reinterpret_cast<const short8*>(vrow[tc] + nb1);
      avn[tc][1] = *reinterpret_cast<const short8*>(vrow[tc] + nb1 + 32);
    }
    // q(it+2); trailing reads spill into kt region — allocated, unused
    aqn0 = *reinterpret_cast<const short8*>(qp + (size_t)(it + 2) * 4096);
    aqn1 = *reinterpret_cast<const short8*>(qp + (size_t)(it + 2) * 4096 + 32);

    short* Esr = (it & 1) ? Es1 : Es0;
    short* Esw = (it & 1) ? Es0 : Es1;

    // QK^T(it+1) — independent of PV(it); results consumed only after PV
    float4v s[4];
    if (it < 63) {
#pragma unroll
      for (int tm = 0; tm < 4; ++tm) {
        float4v t = {0.f, 0.f, 0.f, 0.f};
        t = __builtin_amdgcn_mfma_f32_16x16x32_bf16(aqc0, bkf[tm][0], t, 0, 0, 0);
        t = __builtin_amdgcn_mfma_f32_16x16x32_bf16(aqc1, bkf[tm][1], t, 0, 0, 0);
        s[tm] = t;
      }
    }

    // PV(it)
#pragma unroll
    for (int tm = 0; tm < 4; ++tm) {
      const short8 be0 = *reinterpret_cast<const short8*>(
          &Esr[(tm * 16 + l16) * 72 + quad * 8]);
      const short8 be1 = *reinterpret_cast<const short8*>(
          &Esr[(tm * 16 + l16) * 72 + 32 + quad * 8]);
#pragma unroll
      for (int tc = 0; tc < 4; ++tc) {
        acc[tc][tm] = __builtin_amdgcn_mfma_f32_16x16x32_bf16(avc[tc][0], be0, acc[tc][tm], 0, 0, 0);
        acc[tc][tm] = __builtin_amdgcn_mfma_f32_16x16x32_bf16(avc[tc][1], be1, acc[tc][tm], 0, 0, 0);
      }
    }

    // elu(it+1) -> Es[(it+1)&1]; QK results matured during PV
    if (it < 63) {
#pragma unroll
      for (int tm = 0; tm < 4; ++tm) {
        short4v pk;
#pragma unroll
        for (int r = 0; r < 4; ++r) {
          float sv = s[tm][r];
          sv = (sv > 0.f) ? sv : (__expf(sv) - 1.f);
          pk[r] = f2bf(sv);
        }
        *reinterpret_cast<short4v*>(
            &Esw[(tm * 16 + l16) * 72 + wid * 16 + quad * 4]) = pk;
      }
    }
    __syncthreads();
  };

  for (int it = 0; it < 64; it += 2) {
    seg(it,     avA, avB, aqA0, aqA1, aqB0, aqB1);
    seg(it + 1, avB, avA, aqB0, aqB1, aqA0, aqA1);
  }

  // ---- epilogue: gamma conv via MFMA (INV_N applied here, exact) ----
  // (last seg ended with a barrier; Outs aliasing is safe)
#pragma unroll
  for (int tc = 0; tc < 4; ++tc)
#pragma unroll
    for (int tm = 0; tm < 4; ++tm) {
      short4v pk;
#pragma unroll
      for (int r = 0; r < 4; ++r) pk[r] = f2bf(acc[tc][tm][r] * INV_N);
      *reinterpret_cast<short4v*>(
          &Outs[(tm * 16 + l16) * 264 + wid * 64 + tc * 16 + quad * 4]) = pk;
    }
  __syncthreads();

#pragma unroll
  for (int i = 0; i < 4; ++i)
#pragma unroll
    for (int j = 0; j < 4; ++j) acc[i][j] = float4v{0.f, 0.f, 0.f, 0.f};

  for (int ks8 = 0; ks8 < 8; ++ks8) {
    short8 ag[4];
#pragma unroll
    for (int to = 0; to < 4; ++to)
      ag[to] = *reinterpret_cast<const short8*>(
          &wgb[(size_t)(wid * 64 + to * 16 + l16) * CC + ks8 * 32 + quad * 8]);
    short8 bo[4];
#pragma unroll
    for (int tm = 0; tm < 4; ++tm)
      bo[tm] = *reinterpret_cast<const short8*>(
          &Outs[(tm * 16 + l16) * 264 + ks8 * 32 + quad * 8]);
#pragma unroll
    for (int to = 0; to < 4; ++to)
#pragma unroll
      for (int tm = 0; tm < 4; ++tm)
        acc[to][tm] =
            __builtin_amdgcn_mfma_f32_16x16x32_bf16(ag[to], bo[tm], acc[to][tm], 0, 0, 0);
  }

#pragma unroll
  for (int to = 0; to < 4; ++to) {
#pragma unroll
    for (int r = 0; r < 4; ++r) {
      const int o = wid * 64 + to * 16 + quad * 4 + r;
      const float bgv = bg[o];
#pragma unroll
      for (int tm = 0; tm < 4; ++tm) {
        out[((size_t)b * CC + o) * NN + m0 + tm * 16 + l16] =
            acc[to][tm][r] + bgv;
      }
    }
  }
}

// ---------------------------------------------------------------------------
extern "C" void kernel_launch(void* const* d_in, const int* in_sizes, int n_in,
                              void* d_out, int out_size, void* d_ws,
                              size_t ws_size, hipStream_t stream) {
  const float* x  = (const float*)d_in[0];
  const float* wq = (const float*)d_in[1];
  const float* bq = (const float*)d_in[2];
  const float* wk = (const float*)d_in[3];
  const float* bk = (const float*)d_in[4];
  const float* wv = (const float*)d_in[5];
  const float* bv = (const float*)d_in[6];
  const float* wg = (const float*)d_in[7];
  const float* bg = (const float*)d_in[8];
  float* out = (float*)d_out;

  short* qt  = (short*)d_ws;                     // [B][N][64] bf16, 4 MB
  short* kt  = qt + (size_t)BB * NN * CQ;        // 4 MB
  short* vbf = kt + (size_t)BB * NN * CQ;        // [B][C][N] bf16, 16 MB
  short* wqb = vbf + (size_t)BB * CC * NN;       // bf16 weights, 320 KB total
  short* wkb = wqb + (size_t)CQ * CC;
  short* wvb = wkb + (size_t)CQ * CC;
  short* wgb = wvb + (size_t)CC * CC;

  wconv_kernel<<<dim3(160), 256, 0, stream>>>(wq, wk, wv, wg, wqb, wkb, wvb, wgb);
  qkv_kernel<<<dim3(BB, NN / 64), 256, 0, stream>>>(x, wqb, bq, wkb, bk, wvb, bv,
                                                    qt, kt, vbf);
  attn_kernel<<<dim3(BB, NN / 64), 256, 0, stream>>>(qt, kt, vbf, wgb, bg, out);
}